// Round 10
// baseline (200.267 us; speedup 1.0000x reference)
//
#include <hip/hip_runtime.h>
#include <hip/hip_bf16.h>
#include <math.h>

#define T_SEQ 4096
#define C_DIM 1024
#define H_HEADS 16
#define D_HEAD 64
#define QKVW 3072
#define WIN_HALF 128
#define GLOBAL_TOK 32

typedef __attribute__((ext_vector_type(8))) short bf16x8;
typedef __attribute__((ext_vector_type(4))) float f32x4;

__device__ __forceinline__ float bf2f(unsigned short u) {
    union { unsigned int i; float f; } c; c.i = ((unsigned int)u) << 16; return c.f;
}
__device__ __forceinline__ unsigned short f2bf(float f) {
    union { float f; unsigned int i; } c; c.f = f;
    return (unsigned short)((c.i + 0x7fffu + ((c.i >> 16) & 1u)) >> 16);
}

__device__ __forceinline__ void gll16(const unsigned short* g, unsigned short* l) {
    __builtin_amdgcn_global_load_lds(
        (const __attribute__((address_space(1))) void*)g,
        (__attribute__((address_space(3))) void*)l, 16, 0, 0);
}

// XOR-swizzled element offset into a [64][64] bf16 LDS tile (attn).
__device__ __forceinline__ int swz(int row, int chunk) {
    return row * 64 + ((chunk ^ (row & 7)) * 8);
}

// ---------------------------------------------------------------------------
// Fused prep: x f32->bf16 (blocks [0,4096)), Wa transpose (blocks
// [4096,7168)), Wp transpose (blocks [7168,8192)).
// ---------------------------------------------------------------------------
__global__ __launch_bounds__(256) void prep_kernel(
    const float* __restrict__ x, const float* __restrict__ Wa,
    const float* __restrict__ Wp,
    unsigned short* __restrict__ xb, unsigned short* __restrict__ Wabt,
    unsigned short* __restrict__ Wpbt)
{
    __shared__ unsigned short tile[32][36];
    const int bid = blockIdx.x;
    const int t = threadIdx.x;
    if (bid < 4096) {
        const int idx = bid * 256 + t;
        float4 v = ((const float4*)x)[idx];
        ushort4 o;
        o.x = f2bf(v.x); o.y = f2bf(v.y); o.z = f2bf(v.z); o.w = f2bf(v.w);
        ((ushort4*)xb)[idx] = o;
        return;
    }
    const float* src; unsigned short* dst; int R, Ncols, bx, by;
    if (bid < 4096 + 3072) {
        const int b = bid - 4096;
        src = Wa; dst = Wabt; R = C_DIM; Ncols = QKVW;
        bx = b % (QKVW / 32); by = b / (QKVW / 32);
    } else {
        const int b = bid - 7168;
        src = Wp; dst = Wpbt; R = C_DIM; Ncols = C_DIM;
        bx = b % (C_DIM / 32); by = b / (C_DIM / 32);
    }
    const int r0 = by * 32, c0 = bx * 32;
    const int rr = t >> 3, cq = (t & 7) * 4;
    float4 v = *(const float4*)(src + (size_t)(r0 + rr) * Ncols + c0 + cq);
    tile[rr][cq + 0] = f2bf(v.x); tile[rr][cq + 1] = f2bf(v.y);
    tile[rr][cq + 2] = f2bf(v.z); tile[rr][cq + 3] = f2bf(v.w);
    __syncthreads();
    const int cc = t >> 3, rq = (t & 7) * 4;
    ushort4 o;
    o.x = tile[rq + 0][cc]; o.y = tile[rq + 1][cc];
    o.z = tile[rq + 2][cc]; o.w = tile[rq + 3][cc];
    *(ushort4*)(dst + (size_t)(c0 + cc) * R + r0 + rq) = o;
}

// ---------------------------------------------------------------------------
// GEMM1 (qkv): r10 — BK=32, LDS dbuf 32 KB total -> 4-5 blocks/CU, so the
// 768-block grid completes in ONE residency round (r7's 64 KB dbuf allowed
// only 2/CU: 768 blocks ran as 512+256, half the chip idle in round 2 —
// Occupancy 13.6%). Counted-vmcnt pipeline kept: prologue stages tiles 0,1
// (8 loads/wave in flight); per step wait vmcnt(4) (tile t landed, t+1 in
// flight; never 0 in-loop), barrier, 16 MFMA, barrier, stage t+2.
// Both-sides swizzle for 64B rows: read granule quad^((row>>1)&3), staging
// global-source granule (lane&3)^((lane>>3)&3) — same 8-lane/slot density
// that measured 0 conflicts at BK=64 (r6/r7); 64B coalescing intact.
// WRITE_VT epilogue: n0>=2048 blocks write transposed V to vT[col-2048][m].
// ---------------------------------------------------------------------------
#define GSTAGE32(BUF, KO)                                                      \
  _Pragma("unroll")                                                            \
  for (int i = 0; i < 2; ++i) {                                                \
    const int rb = w * 32 + i * 16;                                            \
    gll16(Ab + (size_t)(rb + srow4) * K + (KO) + sgc, &As[BUF][rb * 32]);      \
    gll16(Bb + (size_t)(rb + srow4) * K + (KO) + sgc, &Bs[BUF][rb * 32]);      \
  }

__global__ __launch_bounds__(256) void gemm_qkv_kernel(
    const unsigned short* __restrict__ A,    // [M,K]
    const unsigned short* __restrict__ Bt,   // [N,K]
    const float* __restrict__ bias,          // [N]
    unsigned short* __restrict__ Cv,         // qkv bf16 [M,N]
    unsigned short* __restrict__ vTp,        // [1024,4096]
    int M, int N, int K)
{
    __shared__ unsigned short As[2][128 * 32];
    __shared__ unsigned short Bs[2][128 * 32];
    const int tid = threadIdx.x;
    const int w = tid >> 6, lane = tid & 63;
    const int quad = lane >> 4, r16 = lane & 15;
    const int m0 = blockIdx.y * 128, n0 = blockIdx.x * 128;
    const int wm = (w & 1) * 64, wn = (w >> 1) * 64;
    // staging ids: each gll16 covers 16 rows (64 lanes x 16B = 1024B); lane
    // covers row rb + (lane>>2), swizzled source granule sgc (16B units).
    const int srow4 = lane >> 2;
    const int sgc = (((lane & 3) ^ ((lane >> 3) & 3))) * 8;

    f32x4 acc[4][4];
    #pragma unroll
    for (int i = 0; i < 4; ++i)
        #pragma unroll
        for (int j = 0; j < 4; ++j) acc[i][j] = (f32x4){0.f, 0.f, 0.f, 0.f};

    const unsigned short* Ab = A + (size_t)m0 * K;
    const unsigned short* Bb = Bt + (size_t)n0 * K;

    const int NS = K / 32;                  // 32
    GSTAGE32(0, 0);
    GSTAGE32(1, 32);

    for (int t = 0; t < NS; ++t) {
        if (t == NS - 1) { asm volatile("s_waitcnt vmcnt(0)" ::: "memory"); }
        else             { asm volatile("s_waitcnt vmcnt(4)" ::: "memory"); }
        __builtin_amdgcn_sched_barrier(0);
        __syncthreads();
        const int cb = t & 1;
        bf16x8 af[4], bf_[4];
        #pragma unroll
        for (int tt = 0; tt < 4; ++tt) {
            const int ra = wm + tt * 16 + r16;
            af[tt]  = *(const bf16x8*)&As[cb][ra * 32 + ((quad ^ ((ra >> 1) & 3)) * 8)];
            const int rb = wn + tt * 16 + r16;
            bf_[tt] = *(const bf16x8*)&Bs[cb][rb * 32 + ((quad ^ ((rb >> 1) & 3)) * 8)];
        }
        __builtin_amdgcn_s_setprio(1);
        #pragma unroll
        for (int mt = 0; mt < 4; ++mt)
            #pragma unroll
            for (int nt = 0; nt < 4; ++nt)
                acc[mt][nt] = __builtin_amdgcn_mfma_f32_16x16x32_bf16(
                    af[mt], bf_[nt], acc[mt][nt], 0, 0, 0);
        __builtin_amdgcn_s_setprio(0);
        if (t + 2 < NS) {
            __syncthreads();
            GSTAGE32(cb, (t + 2) * 32);
        }
    }

    if (n0 >= 2 * C_DIM) {
        // transposed V write: vT[vcol][m], ushort4 runs of 4 m-rows
        #pragma unroll
        for (int nt = 0; nt < 4; ++nt) {
            const int col = n0 + wn + nt * 16 + r16;
            const float bv = bias[col];
            const int vcol = col - 2 * C_DIM;
            #pragma unroll
            for (int mt = 0; mt < 4; ++mt) {
                ushort4 o;
                o.x = f2bf(acc[mt][nt][0] + bv);
                o.y = f2bf(acc[mt][nt][1] + bv);
                o.z = f2bf(acc[mt][nt][2] + bv);
                o.w = f2bf(acc[mt][nt][3] + bv);
                *(ushort4*)&vTp[(size_t)vcol * T_SEQ + m0 + wm + mt * 16 + quad * 4] = o;
            }
        }
    } else {
        #pragma unroll
        for (int nt = 0; nt < 4; ++nt) {
            const int col = n0 + wn + nt * 16 + r16;
            const float bv = bias[col];
            #pragma unroll
            for (int mt = 0; mt < 4; ++mt)
                #pragma unroll
                for (int reg = 0; reg < 4; ++reg) {
                    const int row = m0 + wm + mt * 16 + quad * 4 + reg;
                    Cv[(size_t)row * N + col] = f2bf(acc[mt][nt][reg] + bv);
                }
        }
    }
}

// ---------------------------------------------------------------------------
// GEMM2 (proj): r7 BK=64 body unchanged (grid 256 = 1/CU; residency rounds
// don't apply). f32 out.
// ---------------------------------------------------------------------------
#define GBK 64
#define GSTAGE(BUF, KO)                                                        \
  _Pragma("unroll")                                                            \
  for (int i = 0; i < 4; ++i) {                                                \
    const int r = w * 32 + i * 8 + sr;                                         \
    gll16(Ab + (size_t)r * K + (KO) + sc8, &As[BUF][(w * 32 + i * 8) * GBK]);  \
    gll16(Bb + (size_t)r * K + (KO) + sc8, &Bs[BUF][(w * 32 + i * 8) * GBK]);  \
  }

__global__ __launch_bounds__(256) void gemm_proj_kernel(
    const unsigned short* __restrict__ A,    // [M,K]
    const unsigned short* __restrict__ Bt,   // [N,K]
    const float* __restrict__ bias,          // [N]
    float* __restrict__ Cv, int M, int N, int K)
{
    __shared__ unsigned short As[2][128 * GBK];
    __shared__ unsigned short Bs[2][128 * GBK];
    const int tid = threadIdx.x;
    const int w = tid >> 6, lane = tid & 63;
    const int quad = lane >> 4, r16 = lane & 15;
    const int m0 = blockIdx.y * 128, n0 = blockIdx.x * 128;
    const int wm = (w & 1) * 64, wn = (w >> 1) * 64;
    const int sr = lane >> 3;
    const int sc8 = ((lane & 7) ^ sr) * 8;

    f32x4 acc[4][4];
    #pragma unroll
    for (int i = 0; i < 4; ++i)
        #pragma unroll
        for (int j = 0; j < 4; ++j) acc[i][j] = (f32x4){0.f, 0.f, 0.f, 0.f};

    const unsigned short* Ab = A + (size_t)m0 * K;
    const unsigned short* Bb = Bt + (size_t)n0 * K;

    const int NS = K / GBK;
    GSTAGE(0, 0);
    GSTAGE(1, GBK);

    for (int t = 0; t < NS; ++t) {
        if (t == NS - 1) { asm volatile("s_waitcnt vmcnt(0)" ::: "memory"); }
        else             { asm volatile("s_waitcnt vmcnt(8)" ::: "memory"); }
        __builtin_amdgcn_sched_barrier(0);
        __syncthreads();
        const int cb = t & 1;
        #pragma unroll
        for (int kk = 0; kk < 2; ++kk) {
            bf16x8 af[4], bf_[4];
            #pragma unroll
            for (int tt = 0; tt < 4; ++tt) {
                const int ra = wm + tt * 16 + r16;
                af[tt]  = *(const bf16x8*)&As[cb][ra * GBK + (((kk * 4 + quad) ^ (ra & 7)) * 8)];
                const int rb = wn + tt * 16 + r16;
                bf_[tt] = *(const bf16x8*)&Bs[cb][rb * GBK + (((kk * 4 + quad) ^ (rb & 7)) * 8)];
            }
            #pragma unroll
            for (int mt = 0; mt < 4; ++mt)
                #pragma unroll
                for (int nt = 0; nt < 4; ++nt)
                    acc[mt][nt] = __builtin_amdgcn_mfma_f32_16x16x32_bf16(
                        af[mt], bf_[nt], acc[mt][nt], 0, 0, 0);
        }
        if (t + 2 < NS) {
            __syncthreads();
            GSTAGE(cb, (t + 2) * GBK);
        }
    }

    #pragma unroll
    for (int nt = 0; nt < 4; ++nt) {
        const int col = n0 + wn + nt * 16 + r16;
        const float bv = bias[col];
        #pragma unroll
        for (int mt = 0; mt < 4; ++mt)
            #pragma unroll
            for (int reg = 0; reg < 4; ++reg) {
                const int row = m0 + wm + mt * 16 + quad * 4 + reg;
                Cv[(size_t)row * N + col] = acc[mt][nt][reg] + bv;
            }
    }
}

// ---------------------------------------------------------------------------
// MFMA flash attention (r3 structure + r9 defer-max/deferred-l, verified).
// ---------------------------------------------------------------------------
#define PT_STRIDE 72
#define NSLOT 8
#define PROW 72

struct KVbuf { bf16x8 kl[4], kh[4], vl[4], vh[4]; };
struct StReg { bf16x8 a, b, c, d; };

#define LOAD_KV(C0, B)                                                         \
  {                                                                            \
    const unsigned short* kr_ = kb + (size_t)((C0) + n) * QKVW + quad * 8;     \
    _Pragma("unroll")                                                          \
    for (int g = 0; g < 4; ++g) {                                              \
      B.kl[g] = *(const bf16x8*)(kr_ + (size_t)(g * 16) * QKVW);               \
      B.kh[g] = *(const bf16x8*)(kr_ + (size_t)(g * 16) * QKVW + 32);          \
    }                                                                          \
    const unsigned short* vr_ = vb + (size_t)n * T_SEQ + (C0) + quad * 8;      \
    _Pragma("unroll")                                                          \
    for (int d = 0; d < 4; ++d) {                                              \
      B.vl[d] = *(const bf16x8*)(vr_ + (size_t)(d * 16) * T_SEQ);              \
      B.vh[d] = *(const bf16x8*)(vr_ + (size_t)(d * 16) * T_SEQ + 32);         \
    }                                                                          \
  }

// mm = lane-local max of this tile's 16 (scaled/masked) scores.
// Rescale path: only when some lane exceeds m_run+8 (wave-uniform branch).
#define SOFTMAX_P_UPDATE(StV)                                                  \
    if (!__all(mm <= m_run + 8.f)) {                                           \
      float mx_ = fmaxf(mm, __shfl_xor(mm, 16));                               \
      mx_ = fmaxf(mx_, __shfl_xor(mx_, 32));                                   \
      const float mn_ = fmaxf(m_run, mx_);                                     \
      const float al_ = __expf(m_run - mn_);                                   \
      l_part *= al_;                                                           \
      _Pragma("unroll")                                                        \
      for (int d = 0; d < 4; ++d)                                              \
        _Pragma("unroll")                                                      \
        for (int r = 0; r < 4; ++r) O[d][r] *= al_;                            \
      m_run = mn_;                                                             \
    }                                                                          \
    {                                                                          \
      const float mnf = m_run;                                                 \
      float rs = 0.f;                                                          \
      _Pragma("unroll")                                                        \
      for (int g = 0; g < 4; ++g) {                                            \
        const float e0 = __expf(StV[g][0] - mnf);                              \
        const float e1 = __expf(StV[g][1] - mnf);                              \
        const float e2 = __expf(StV[g][2] - mnf);                              \
        const float e3 = __expf(StV[g][3] - mnf);                              \
        rs += (e0 + e1) + (e2 + e3);                                           \
        const unsigned int p01 = f2bf(e0) | ((unsigned int)f2bf(e1) << 16);    \
        const unsigned int p23 = f2bf(e2) | ((unsigned int)f2bf(e3) << 16);    \
        *(unsigned int*)&myPt[n * PT_STRIDE + g * 16 + quad * 4] = p01;        \
        *(unsigned int*)&myPt[n * PT_STRIDE + g * 16 + quad * 4 + 2] = p23;    \
      }                                                                        \
      l_part += rs;                                                            \
    }

#define PROC_TILE(ITV, CUR, NXT)                                               \
  {                                                                            \
    const int it_ = (ITV);                                                     \
    const int c0 = split * 512 + it_ * 64;                                     \
    f32x4 St[4];                                                               \
    __builtin_amdgcn_s_setprio(1);                                             \
    _Pragma("unroll")                                                          \
    for (int g = 0; g < 4; ++g) {                                              \
      St[g] = __builtin_amdgcn_mfma_f32_16x16x32_bf16(CUR.kl[g], q0, Zf, 0, 0, 0); \
      St[g] = __builtin_amdgcn_mfma_f32_16x16x32_bf16(CUR.kh[g], q1, St[g], 0, 0, 0); \
    }                                                                          \
    __builtin_amdgcn_s_setprio(0);                                             \
    if (it_ + 1 < n_tiles) {                                                   \
      LOAD_KV(c0 + 64, NXT);                                                   \
    }                                                                          \
    float mm = -INFINITY;                                                      \
    _Pragma("unroll")                                                          \
    for (int g = 0; g < 4; ++g)                                                \
      _Pragma("unroll")                                                        \
      for (int r = 0; r < 4; ++r) {                                            \
        const float v = St[g][r] * 0.125f;                                     \
        St[g][r] = v; mm = fmaxf(mm, v);                                       \
      }                                                                        \
    SOFTMAX_P_UPDATE(St)                                                       \
    asm volatile("s_waitcnt lgkmcnt(0)" ::: "memory");                         \
    __builtin_amdgcn_sched_barrier(0);                                         \
    __builtin_amdgcn_s_setprio(1);                                             \
    _Pragma("unroll")                                                          \
    for (int kg = 0; kg < 2; ++kg) {                                           \
      bf16x8 pf_ = *(const bf16x8*)&myPt[n * PT_STRIDE + kg * 32 + quad * 8];  \
      _Pragma("unroll")                                                        \
      for (int d = 0; d < 4; ++d)                                              \
        O[d] = __builtin_amdgcn_mfma_f32_16x16x32_bf16(                        \
            kg ? CUR.vh[d] : CUR.vl[d], pf_, O[d], 0, 0, 0);                   \
    }                                                                          \
    __builtin_amdgcn_s_setprio(0);                                             \
  }

#define STAGE_LOAD(C0, R)                                                      \
  { const int c0s_ = (C0);                                                     \
    R.a = *(const bf16x8*)(kb + (size_t)(c0s_ + srow) * QKVW + scol * 8);      \
    R.b = *(const bf16x8*)(kb + (size_t)(c0s_ + srow + 32) * QKVW + scol * 8); \
    R.c = *(const bf16x8*)(vb + (size_t)srow * T_SEQ + c0s_ + scol * 8);       \
    R.d = *(const bf16x8*)(vb + (size_t)(srow + 32) * T_SEQ + c0s_ + scol * 8); }

#define STAGE_WRITE(BUF, R)                                                    \
  { *(bf16x8*)&Ks[BUF][kdst0] = R.a;                                           \
    *(bf16x8*)&Ks[BUF][kdst1] = R.b;                                           \
    *(bf16x8*)&Vs[BUF][kdst0] = R.c;                                           \
    *(bf16x8*)&Vs[BUF][kdst1] = R.d; }

#define WTILE(ITV, BUF, RW, RL)                                                \
  {                                                                            \
    const int it_ = (ITV);                                                     \
    const int c0 = (it_ == 0) ? 0 : (blo + (it_ - 1) * 64);                    \
    if (activeW) {                                                             \
      bf16x8 kl[4], kh[4];                                                     \
      _Pragma("unroll")                                                        \
      for (int g = 0; g < 4; ++g) {                                            \
        kl[g] = *(const bf16x8*)&Ks[BUF][swz(n + g * 16, quad)];               \
        kh[g] = *(const bf16x8*)&Ks[BUF][swz(n + g * 16, quad + 4)];           \
      }                                                                        \
      f32x4 St[4];                                                             \
      __builtin_amdgcn_s_setprio(1);                                           \
      _Pragma("unroll")                                                        \
      for (int g = 0; g < 4; ++g) {                                            \
        St[g] = __builtin_amdgcn_mfma_f32_16x16x32_bf16(kl[g], q0, Zf, 0, 0, 0); \
        St[g] = __builtin_amdgcn_mfma_f32_16x16x32_bf16(kh[g], q1, St[g], 0, 0, 0); \
      }                                                                        \
      __builtin_amdgcn_s_setprio(0);                                           \
      float mm = -INFINITY;                                                    \
      if (it_ != 0 && c0 >= rowbase - 113 && c0 <= rowbase + 65) {             \
        _Pragma("unroll")                                                      \
        for (int g = 0; g < 4; ++g)                                            \
          _Pragma("unroll")                                                    \
          for (int r = 0; r < 4; ++r) {                                        \
            const float v = St[g][r] * 0.125f;                                 \
            St[g][r] = v; mm = fmaxf(mm, v);                                   \
          }                                                                    \
      } else if (it_ == 0 && rowbase >= 192) {                                 \
        _Pragma("unroll")                                                      \
        for (int g = 0; g < 2; ++g)                                            \
          _Pragma("unroll")                                                    \
          for (int r = 0; r < 4; ++r) {                                        \
            const float v = St[g][r] * 0.125f;                                 \
            St[g][r] = v; mm = fmaxf(mm, v);                                   \
          }                                                                    \
        _Pragma("unroll")                                                      \
        for (int g = 2; g < 4; ++g)                                            \
          _Pragma("unroll")                                                    \
          for (int r = 0; r < 4; ++r) St[g][r] = -INFINITY;                    \
      } else {                                                                 \
        _Pragma("unroll")                                                      \
        for (int g = 0; g < 4; ++g)                                            \
          _Pragma("unroll")                                                    \
          for (int r = 0; r < 4; ++r) {                                        \
            float v = St[g][r] * 0.125f;                                       \
            const int col = c0 + g * 16 + quad * 4 + r;                        \
            int dd = row - col; dd = dd < 0 ? -dd : dd;                        \
            if (!(col < GLOBAL_TOK || dd <= WIN_HALF)) v = -INFINITY;          \
            St[g][r] = v; mm = fmaxf(mm, v);                                   \
          }                                                                    \
      }                                                                        \
      SOFTMAX_P_UPDATE(St)                                                     \
      bf16x8 vl[4], vh[4];                                                     \
      _Pragma("unroll")                                                        \
      for (int d = 0; d < 4; ++d) {                                            \
        vl[d] = *(const bf16x8*)&Vs[BUF][swz(n + d * 16, quad)];               \
        vh[d] = *(const bf16x8*)&Vs[BUF][swz(n + d * 16, quad + 4)];           \
      }                                                                        \
      asm volatile("s_waitcnt lgkmcnt(0)" ::: "memory");                       \
      __builtin_amdgcn_sched_barrier(0);                                       \
      __builtin_amdgcn_s_setprio(1);                                           \
      _Pragma("unroll")                                                        \
      for (int kg = 0; kg < 2; ++kg) {                                         \
        bf16x8 pf_ = *(const bf16x8*)&myPt[n * PT_STRIDE + kg * 32 + quad * 8];\
        _Pragma("unroll")                                                      \
        for (int d = 0; d < 4; ++d)                                            \
          O[d] = __builtin_amdgcn_mfma_f32_16x16x32_bf16(                      \
              kg ? vh[d] : vl[d], pf_, O[d], 0, 0, 0);                         \
      }                                                                        \
      __builtin_amdgcn_s_setprio(0);                                           \
    }                                                                          \
    if (it_ + 1 < NT) {                                                        \
      asm volatile("s_waitcnt vmcnt(0)" ::: "memory");                         \
      __builtin_amdgcn_sched_barrier(0);                                       \
      STAGE_WRITE((BUF) ^ 1, RW);                                              \
      if (it_ + 2 < NT) { STAGE_LOAD(blo + (it_ + 1) * 64, RL); }              \
      __syncthreads();                                                         \
    }                                                                          \
  }

__global__ __launch_bounds__(256, 3) void sparse_attn_mfma(
    const unsigned short* __restrict__ qkv,
    const unsigned short* __restrict__ vT,
    unsigned short* __restrict__ y,
    float* __restrict__ part)
{
    __shared__ unsigned short Ks[2][64 * 64];
    __shared__ unsigned short Vs[2][64 * 64];
    __shared__ unsigned short Pt[4][16 * PT_STRIDE];
    const int tid = threadIdx.x;
    const int w = tid >> 6, lane = tid & 63;
    const int quad = lane >> 4, n = lane & 15;
    const int bid = blockIdx.x;
    const f32x4 Zf = (f32x4){0.f, 0.f, 0.f, 0.f};

    if (bid < 1024) {
        // ---------------- windowed block path ----------------
        const int h = bid & 15;
        const int B = bid >> 4;            // [0,64)
        const int base = B * 64;
        const int rowbase = base + w * 16;
        const bool activeW = !(B == 0 && w < 2);   // rows 0-31 -> dense path
        int blo = base - 128; if (blo < 64) blo = 64;
        int bhi = base + 192; if (bhi > T_SEQ) bhi = T_SEQ;
        const int NT = 1 + (bhi - blo) / 64;

        const unsigned short* kb = qkv + C_DIM + h * 64;
        const unsigned short* vb = vT + (size_t)h * 64 * T_SEQ;
        unsigned short* myPt = Pt[w];

        const int srow = tid >> 3, scol = tid & 7;
        const int kdst0 = swz(srow, scol);
        const int kdst1 = kdst0 + 32 * 64;

        const unsigned short* qp = qkv + (size_t)(rowbase + n) * QKVW + h * 64 + quad * 8;
        bf16x8 q0 = *(const bf16x8*)qp;
        bf16x8 q1 = *(const bf16x8*)(qp + 32);

        f32x4 O[4];
        #pragma unroll
        for (int i = 0; i < 4; ++i) O[i] = (f32x4){0.f, 0.f, 0.f, 0.f};
        float m_run = -INFINITY, l_part = 0.f;
        const int row = rowbase + n;

        StReg r0, r1;
        STAGE_LOAD(0, r0);                 // tile 0 (global cols)
        asm volatile("s_waitcnt vmcnt(0)" ::: "memory");
        __builtin_amdgcn_sched_barrier(0);
        STAGE_WRITE(0, r0);
        STAGE_LOAD(blo, r1);               // tile 1 (NT >= 3 always)
        __syncthreads();

        int it = 0;
        for (;;) {
            WTILE(it, 0, r1, r0);
            if (++it >= NT) break;
            WTILE(it, 1, r0, r1);
            if (++it >= NT) break;
        }

        if (activeW) {
            float l_run = l_part;
            l_run += __shfl_xor(l_run, 16);
            l_run += __shfl_xor(l_run, 32);
            const float invL = 1.f / l_run;
            #pragma unroll
            for (int dblk = 0; dblk < 4; ++dblk)
                #pragma unroll
                for (int r = 0; r < 4; ++r)
                    y[(size_t)row * C_DIM + h * 64 + dblk * 16 + quad * 4 + r] =
                        f2bf(O[dblk][r] * invL);
        }
    } else {
        // ---------------- dense split-K path (rows 0-31) ----------------
        const int idx = bid - 1024;        // [0,64)
        const int h = idx & 15;
        const int u = (idx >> 4) * 4 + w;  // [0,16)
        const int rt = u >> 3, split = u & 7;
        const int rowbase = rt * 16;
        const int n_tiles = 8;

        const unsigned short* qp = qkv + (size_t)(rowbase + n) * QKVW + h * 64 + quad * 8;
        bf16x8 q0 = *(const bf16x8*)qp;
        bf16x8 q1 = *(const bf16x8*)(qp + 32);

        const unsigned short* kb = qkv + C_DIM + h * 64;
        const unsigned short* vb = vT + (size_t)h * 64 * T_SEQ;
        unsigned short* myPt = Pt[w];

        f32x4 O[4];
        #pragma unroll
        for (int i = 0; i < 4; ++i) O[i] = (f32x4){0.f, 0.f, 0.f, 0.f};
        float m_run = -INFINITY, l_part = 0.f;

        KVbuf b0, b1;
        LOAD_KV(split * 512, b0);
        int it = 0;
        for (;;) {
            PROC_TILE(it, b0, b1);
            if (++it >= n_tiles) break;
            PROC_TILE(it, b1, b0);
            if (++it >= n_tiles) break;
        }

        float l_run = l_part;
        l_run += __shfl_xor(l_run, 16);
        l_run += __shfl_xor(l_run, 32);

        float* pb = part + ((size_t)(h * 2 + rt) * NSLOT + split) * 16 * PROW;
        #pragma unroll
        for (int dblk = 0; dblk < 4; ++dblk)
            #pragma unroll
            for (int r = 0; r < 4; ++r)
                pb[n * PROW + dblk * 16 + quad * 4 + r] = O[dblk][r];
        if (quad == 0) {
            pb[n * PROW + 64] = m_run;
            pb[n * PROW + 65] = l_run;
        }
    }
}

// Merge NSLOT partials per (head, 16-row tile) -> y rows 0..31.
__global__ __launch_bounds__(64) void attn_combine(
    const float* __restrict__ part, unsigned short* __restrict__ y)
{
    const int d = threadIdx.x;
    const int h = blockIdx.x >> 1, rt = blockIdx.x & 1;
    const float* base = part + (size_t)(h * 2 + rt) * NSLOT * 16 * PROW;
    for (int row = 0; row < 16; ++row) {
        float M = -INFINITY;
        for (int sl = 0; sl < NSLOT; ++sl)
            M = fmaxf(M, base[(size_t)sl * 16 * PROW + row * PROW + 64]);
        float L = 0.f, Od = 0.f;
        for (int sl = 0; sl < NSLOT; ++sl) {
            const float* p = base + (size_t)sl * 16 * PROW + row * PROW;
            const float s = __expf(p[64] - M);
            L += p[65] * s;
            Od += p[d] * s;
        }
        y[(size_t)(rt * 16 + row) * C_DIM + h * 64 + d] = f2bf(Od / L);
    }
}

extern "C" void kernel_launch(void* const* d_in, const int* in_sizes, int n_in,
                              void* d_out, int out_size, void* d_ws, size_t ws_size,
                              hipStream_t stream) {
    const float* x  = (const float*)d_in[0];
    const float* Wa = (const float*)d_in[1];
    const float* ba = (const float*)d_in[2];
    const float* Wp = (const float*)d_in[3];
    const float* bp = (const float*)d_in[4];
    float* out = (float*)d_out;

    // ws layout (ushort units):
    // xb 8MB, Wabt 6MB, Wpbt 2MB, qkv 24MB, yat 8MB, vT 8MB, part 1.2MB
    unsigned short* xb   = (unsigned short*)d_ws;                   // [4096,1024]
    unsigned short* Wabt = xb   + (size_t)T_SEQ * C_DIM;            // [3072,1024]
    unsigned short* Wpbt = Wabt + (size_t)C_DIM * QKVW;             // [1024,1024]
    unsigned short* qkv  = Wpbt + (size_t)C_DIM * C_DIM;            // [4096,3072]
    unsigned short* yat  = qkv  + (size_t)T_SEQ * QKVW;             // [4096,1024]
    unsigned short* vT   = yat  + (size_t)T_SEQ * C_DIM;            // [1024,4096]
    float* part = (float*)(vT + (size_t)C_DIM * T_SEQ);

    prep_kernel<<<4096 + 3072 + 1024, 256, 0, stream>>>(
        x, Wa, Wp, xb, Wabt, Wpbt);

    gemm_qkv_kernel<<<dim3(QKVW / 128, T_SEQ / 128), 256, 0, stream>>>(
        xb, Wabt, ba, qkv, vT, T_SEQ, QKVW, C_DIM);

    const int nBlocks = 1024 + 64;   // normal + dense split-K
    sparse_attn_mfma<<<nBlocks, 256, 0, stream>>>(qkv, vT, yat, part);
    attn_combine<<<H_HEADS * 2, 64, 0, stream>>>(part, yat);

    gemm_proj_kernel<<<dim3(C_DIM / 128, T_SEQ / 128), 256, 0, stream>>>(
        yat, Wpbt, bp, out, T_SEQ, C_DIM, C_DIM);
}

// Round 12
// 186.098 us; speedup vs baseline: 1.0761x; 1.0761x over previous
//
#include <hip/hip_runtime.h>
#include <hip/hip_bf16.h>
#include <math.h>

#define T_SEQ 4096
#define C_DIM 1024
#define H_HEADS 16
#define D_HEAD 64
#define QKVW 3072
#define WIN_HALF 128
#define GLOBAL_TOK 32

typedef __attribute__((ext_vector_type(8))) short bf16x8;
typedef __attribute__((ext_vector_type(4))) float f32x4;

__device__ __forceinline__ float bf2f(unsigned short u) {
    union { unsigned int i; float f; } c; c.i = ((unsigned int)u) << 16; return c.f;
}
__device__ __forceinline__ unsigned short f2bf(float f) {
    union { float f; unsigned int i; } c; c.f = f;
    return (unsigned short)((c.i + 0x7fffu + ((c.i >> 16) & 1u)) >> 16);
}

__device__ __forceinline__ void gll16(const unsigned short* g, unsigned short* l) {
    __builtin_amdgcn_global_load_lds(
        (const __attribute__((address_space(1))) void*)g,
        (__attribute__((address_space(3))) void*)l, 16, 0, 0);
}

// XOR-swizzled element offset into a [64][64] bf16 LDS tile (attn).
__device__ __forceinline__ int swz(int row, int chunk) {
    return row * 64 + ((chunk ^ (row & 7)) * 8);
}

// ---------------------------------------------------------------------------
// Fused prep: x f32->bf16 (blocks [0,4096)), Wa transpose (blocks
// [4096,7168)), Wp transpose (blocks [7168,8192)).
// ---------------------------------------------------------------------------
__global__ __launch_bounds__(256) void prep_kernel(
    const float* __restrict__ x, const float* __restrict__ Wa,
    const float* __restrict__ Wp,
    unsigned short* __restrict__ xb, unsigned short* __restrict__ Wabt,
    unsigned short* __restrict__ Wpbt)
{
    __shared__ unsigned short tile[32][36];
    const int bid = blockIdx.x;
    const int t = threadIdx.x;
    if (bid < 4096) {
        const int idx = bid * 256 + t;
        float4 v = ((const float4*)x)[idx];
        ushort4 o;
        o.x = f2bf(v.x); o.y = f2bf(v.y); o.z = f2bf(v.z); o.w = f2bf(v.w);
        ((ushort4*)xb)[idx] = o;
        return;
    }
    const float* src; unsigned short* dst; int R, Ncols, bx, by;
    if (bid < 4096 + 3072) {
        const int b = bid - 4096;
        src = Wa; dst = Wabt; R = C_DIM; Ncols = QKVW;
        bx = b % (QKVW / 32); by = b / (QKVW / 32);
    } else {
        const int b = bid - 7168;
        src = Wp; dst = Wpbt; R = C_DIM; Ncols = C_DIM;
        bx = b % (C_DIM / 32); by = b / (C_DIM / 32);
    }
    const int r0 = by * 32, c0 = bx * 32;
    const int rr = t >> 3, cq = (t & 7) * 4;
    float4 v = *(const float4*)(src + (size_t)(r0 + rr) * Ncols + c0 + cq);
    tile[rr][cq + 0] = f2bf(v.x); tile[rr][cq + 1] = f2bf(v.y);
    tile[rr][cq + 2] = f2bf(v.z); tile[rr][cq + 3] = f2bf(v.w);
    __syncthreads();
    const int cc = t >> 3, rq = (t & 7) * 4;
    ushort4 o;
    o.x = tile[rq + 0][cc]; o.y = tile[rq + 1][cc];
    o.z = tile[rq + 2][cc]; o.w = tile[rq + 3][cc];
    *(ushort4*)(dst + (size_t)(c0 + cc) * R + r0 + rq) = o;
}

// ---------------------------------------------------------------------------
// GEMM bodies: r7 128^2 x BK=64, counted vmcnt(8) pipeline — bench-verified
// 42.8 us (r10's BK=32 regressed ~9 us: doubled barrier/wait count beat the
// extra resident blocks). Both-sides XOR swizzle: bank-conflict 0 (counters).
// WRITE_VT: n0>=2048 blocks (V third) write transposed V to vT[col-2048][m].
// ---------------------------------------------------------------------------
#define GBK 64
#define GSTAGE(BUF, KO)                                                        \
  _Pragma("unroll")                                                            \
  for (int i = 0; i < 4; ++i) {                                                \
    const int r = w * 32 + i * 8 + sr;                                         \
    gll16(Ab + (size_t)r * K + (KO) + sc8, &As[BUF][(w * 32 + i * 8) * GBK]);  \
    gll16(Bb + (size_t)r * K + (KO) + sc8, &Bs[BUF][(w * 32 + i * 8) * GBK]);  \
  }

template<int OUT_BF16, int WRITE_VT>
__device__ __forceinline__ void gemm_body(
    const unsigned short* __restrict__ A,    // [M,K]
    const unsigned short* __restrict__ Bt,   // [N,K]
    const float* __restrict__ bias,          // [N]
    void* __restrict__ Cv, unsigned short* __restrict__ vTp,
    int M, int N, int K)
{
    __shared__ unsigned short As[2][128 * GBK];
    __shared__ unsigned short Bs[2][128 * GBK];
    const int tid = threadIdx.x;
    const int w = tid >> 6, lane = tid & 63;
    const int quad = lane >> 4, r16 = lane & 15;
    const int m0 = blockIdx.y * 128, n0 = blockIdx.x * 128;
    const int wm = (w & 1) * 64, wn = (w >> 1) * 64;
    const int sr = lane >> 3;
    const int sc8 = ((lane & 7) ^ sr) * 8;

    f32x4 acc[4][4];
    #pragma unroll
    for (int i = 0; i < 4; ++i)
        #pragma unroll
        for (int j = 0; j < 4; ++j) acc[i][j] = (f32x4){0.f, 0.f, 0.f, 0.f};

    const unsigned short* Ab = A + (size_t)m0 * K;
    const unsigned short* Bb = Bt + (size_t)n0 * K;

    const int NS = K / GBK;                 // 16
    GSTAGE(0, 0);
    GSTAGE(1, GBK);

    for (int t = 0; t < NS; ++t) {
        if (t == NS - 1) { asm volatile("s_waitcnt vmcnt(0)" ::: "memory"); }
        else             { asm volatile("s_waitcnt vmcnt(8)" ::: "memory"); }
        __builtin_amdgcn_sched_barrier(0);
        __syncthreads();
        const int cb = t & 1;
        #pragma unroll
        for (int kk = 0; kk < 2; ++kk) {
            bf16x8 af[4], bf_[4];
            #pragma unroll
            for (int tt = 0; tt < 4; ++tt) {
                const int ra = wm + tt * 16 + r16;
                af[tt]  = *(const bf16x8*)&As[cb][ra * GBK + (((kk * 4 + quad) ^ (ra & 7)) * 8)];
                const int rb = wn + tt * 16 + r16;
                bf_[tt] = *(const bf16x8*)&Bs[cb][rb * GBK + (((kk * 4 + quad) ^ (rb & 7)) * 8)];
            }
            #pragma unroll
            for (int mt = 0; mt < 4; ++mt)
                #pragma unroll
                for (int nt = 0; nt < 4; ++nt)
                    acc[mt][nt] = __builtin_amdgcn_mfma_f32_16x16x32_bf16(
                        af[mt], bf_[nt], acc[mt][nt], 0, 0, 0);
        }
        if (t + 2 < NS) {
            __syncthreads();
            GSTAGE(cb, (t + 2) * GBK);
        }
    }

    if (WRITE_VT && n0 >= 2 * C_DIM) {
        // transposed V write: vT[vcol][m], ushort4 runs of 4 m-rows
        #pragma unroll
        for (int nt = 0; nt < 4; ++nt) {
            const int col = n0 + wn + nt * 16 + r16;
            const float bv = bias[col];
            const int vcol = col - 2 * C_DIM;
            #pragma unroll
            for (int mt = 0; mt < 4; ++mt) {
                ushort4 o;
                o.x = f2bf(acc[mt][nt][0] + bv);
                o.y = f2bf(acc[mt][nt][1] + bv);
                o.z = f2bf(acc[mt][nt][2] + bv);
                o.w = f2bf(acc[mt][nt][3] + bv);
                *(ushort4*)&vTp[(size_t)vcol * T_SEQ + m0 + wm + mt * 16 + quad * 4] = o;
            }
        }
    } else {
        #pragma unroll
        for (int nt = 0; nt < 4; ++nt) {
            const int col = n0 + wn + nt * 16 + r16;
            const float bv = bias[col];
            #pragma unroll
            for (int mt = 0; mt < 4; ++mt)
                #pragma unroll
                for (int reg = 0; reg < 4; ++reg) {
                    const int row = m0 + wm + mt * 16 + quad * 4 + reg;
                    if (OUT_BF16)
                        ((unsigned short*)Cv)[(size_t)row * N + col] = f2bf(acc[mt][nt][reg] + bv);
                    else
                        ((float*)Cv)[(size_t)row * N + col] = acc[mt][nt][reg] + bv;
                }
        }
    }
}

__global__ __launch_bounds__(256) void gemm_qkv_kernel(
    const unsigned short* __restrict__ A, const unsigned short* __restrict__ Bt,
    const float* __restrict__ bias, void* __restrict__ Cv,
    unsigned short* __restrict__ vTp, int M, int N, int K)
{
    gemm_body<1, 1>(A, Bt, bias, Cv, vTp, M, N, K);
}
__global__ __launch_bounds__(256) void gemm_proj_kernel(
    const unsigned short* __restrict__ A, const unsigned short* __restrict__ Bt,
    const float* __restrict__ bias, void* __restrict__ Cv,
    unsigned short* __restrict__ vTp, int M, int N, int K)
{
    gemm_body<0, 0>(A, Bt, bias, Cv, vTp, M, N, K);
}

// ---------------------------------------------------------------------------
// MFMA flash attention (r3 structure + r9 defer-max/deferred-l).
// r11: dense split-K blocks dispatched FIRST (bid<64) — previously they were
// last (bid>=1024) and ran as a 64-block tail on a 256-CU chip after the
// windowed blocks drained (avg occupancy 9%). Now they overlap the windowed
// bulk. Windowed blocks: bid-64 -> (head, 64-row band). Pure index remap.
// ---------------------------------------------------------------------------
#define PT_STRIDE 72
#define NSLOT 8
#define PROW 72

struct KVbuf { bf16x8 kl[4], kh[4], vl[4], vh[4]; };
struct StReg { bf16x8 a, b, c, d; };

#define LOAD_KV(C0, B)                                                         \
  {                                                                            \
    const unsigned short* kr_ = kb + (size_t)((C0) + n) * QKVW + quad * 8;     \
    _Pragma("unroll")                                                          \
    for (int g = 0; g < 4; ++g) {                                              \
      B.kl[g] = *(const bf16x8*)(kr_ + (size_t)(g * 16) * QKVW);               \
      B.kh[g] = *(const bf16x8*)(kr_ + (size_t)(g * 16) * QKVW + 32);          \
    }                                                                          \
    const unsigned short* vr_ = vb + (size_t)n * T_SEQ + (C0) + quad * 8;      \
    _Pragma("unroll")                                                          \
    for (int d = 0; d < 4; ++d) {                                              \
      B.vl[d] = *(const bf16x8*)(vr_ + (size_t)(d * 16) * T_SEQ);              \
      B.vh[d] = *(const bf16x8*)(vr_ + (size_t)(d * 16) * T_SEQ + 32);         \
    }                                                                          \
  }

// mm = lane-local max of this tile's 16 (scaled/masked) scores.
// Rescale path: only when some lane exceeds m_run+8 (wave-uniform branch).
#define SOFTMAX_P_UPDATE(StV)                                                  \
    if (!__all(mm <= m_run + 8.f)) {                                           \
      float mx_ = fmaxf(mm, __shfl_xor(mm, 16));                               \
      mx_ = fmaxf(mx_, __shfl_xor(mx_, 32));                                   \
      const float mn_ = fmaxf(m_run, mx_);                                     \
      const float al_ = __expf(m_run - mn_);                                   \
      l_part *= al_;                                                           \
      _Pragma("unroll")                                                        \
      for (int d = 0; d < 4; ++d)                                              \
        _Pragma("unroll")                                                      \
        for (int r = 0; r < 4; ++r) O[d][r] *= al_;                            \
      m_run = mn_;                                                             \
    }                                                                          \
    {                                                                          \
      const float mnf = m_run;                                                 \
      float rs = 0.f;                                                          \
      _Pragma("unroll")                                                        \
      for (int g = 0; g < 4; ++g) {                                            \
        const float e0 = __expf(StV[g][0] - mnf);                              \
        const float e1 = __expf(StV[g][1] - mnf);                              \
        const float e2 = __expf(StV[g][2] - mnf);                              \
        const float e3 = __expf(StV[g][3] - mnf);                              \
        rs += (e0 + e1) + (e2 + e3);                                           \
        const unsigned int p01 = f2bf(e0) | ((unsigned int)f2bf(e1) << 16);    \
        const unsigned int p23 = f2bf(e2) | ((unsigned int)f2bf(e3) << 16);    \
        *(unsigned int*)&myPt[n * PT_STRIDE + g * 16 + quad * 4] = p01;        \
        *(unsigned int*)&myPt[n * PT_STRIDE + g * 16 + quad * 4 + 2] = p23;    \
      }                                                                        \
      l_part += rs;                                                            \
    }

#define PROC_TILE(ITV, CUR, NXT)                                               \
  {                                                                            \
    const int it_ = (ITV);                                                     \
    const int c0 = split * 512 + it_ * 64;                                     \
    f32x4 St[4];                                                               \
    __builtin_amdgcn_s_setprio(1);                                             \
    _Pragma("unroll")                                                          \
    for (int g = 0; g < 4; ++g) {                                              \
      St[g] = __builtin_amdgcn_mfma_f32_16x16x32_bf16(CUR.kl[g], q0, Zf, 0, 0, 0); \
      St[g] = __builtin_amdgcn_mfma_f32_16x16x32_bf16(CUR.kh[g], q1, St[g], 0, 0, 0); \
    }                                                                          \
    __builtin_amdgcn_s_setprio(0);                                             \
    if (it_ + 1 < n_tiles) {                                                   \
      LOAD_KV(c0 + 64, NXT);                                                   \
    }                                                                          \
    float mm = -INFINITY;                                                      \
    _Pragma("unroll")                                                          \
    for (int g = 0; g < 4; ++g)                                                \
      _Pragma("unroll")                                                        \
      for (int r = 0; r < 4; ++r) {                                            \
        const float v = St[g][r] * 0.125f;                                     \
        St[g][r] = v; mm = fmaxf(mm, v);                                       \
      }                                                                        \
    SOFTMAX_P_UPDATE(St)                                                       \
    asm volatile("s_waitcnt lgkmcnt(0)" ::: "memory");                         \
    __builtin_amdgcn_sched_barrier(0);                                         \
    __builtin_amdgcn_s_setprio(1);                                             \
    _Pragma("unroll")                                                          \
    for (int kg = 0; kg < 2; ++kg) {                                           \
      bf16x8 pf_ = *(const bf16x8*)&myPt[n * PT_STRIDE + kg * 32 + quad * 8];  \
      _Pragma("unroll")                                                        \
      for (int d = 0; d < 4; ++d)                                              \
        O[d] = __builtin_amdgcn_mfma_f32_16x16x32_bf16(                        \
            kg ? CUR.vh[d] : CUR.vl[d], pf_, O[d], 0, 0, 0);                   \
    }                                                                          \
    __builtin_amdgcn_s_setprio(0);                                             \
  }

#define STAGE_LOAD(C0, R)                                                      \
  { const int c0s_ = (C0);                                                     \
    R.a = *(const bf16x8*)(kb + (size_t)(c0s_ + srow) * QKVW + scol * 8);      \
    R.b = *(const bf16x8*)(kb + (size_t)(c0s_ + srow + 32) * QKVW + scol * 8); \
    R.c = *(const bf16x8*)(vb + (size_t)srow * T_SEQ + c0s_ + scol * 8);       \
    R.d = *(const bf16x8*)(vb + (size_t)(srow + 32) * T_SEQ + c0s_ + scol * 8); }

#define STAGE_WRITE(BUF, R)                                                    \
  { *(bf16x8*)&Ks[BUF][kdst0] = R.a;                                           \
    *(bf16x8*)&Ks[BUF][kdst1] = R.b;                                           \
    *(bf16x8*)&Vs[BUF][kdst0] = R.c;                                           \
    *(bf16x8*)&Vs[BUF][kdst1] = R.d; }

#define WTILE(ITV, BUF, RW, RL)                                                \
  {                                                                            \
    const int it_ = (ITV);                                                     \
    const int c0 = (it_ == 0) ? 0 : (blo + (it_ - 1) * 64);                    \
    if (activeW) {                                                             \
      bf16x8 kl[4], kh[4];                                                     \
      _Pragma("unroll")                                                        \
      for (int g = 0; g < 4; ++g) {                                            \
        kl[g] = *(const bf16x8*)&Ks[BUF][swz(n + g * 16, quad)];               \
        kh[g] = *(const bf16x8*)&Ks[BUF][swz(n + g * 16, quad + 4)];           \
      }                                                                        \
      f32x4 St[4];                                                             \
      __builtin_amdgcn_s_setprio(1);                                           \
      _Pragma("unroll")                                                        \
      for (int g = 0; g < 4; ++g) {                                            \
        St[g] = __builtin_amdgcn_mfma_f32_16x16x32_bf16(kl[g], q0, Zf, 0, 0, 0); \
        St[g] = __builtin_amdgcn_mfma_f32_16x16x32_bf16(kh[g], q1, St[g], 0, 0, 0); \
      }                                                                        \
      __builtin_amdgcn_s_setprio(0);                                           \
      float mm = -INFINITY;                                                    \
      if (it_ != 0 && c0 >= rowbase - 113 && c0 <= rowbase + 65) {             \
        _Pragma("unroll")                                                      \
        for (int g = 0; g < 4; ++g)                                            \
          _Pragma("unroll")                                                    \
          for (int r = 0; r < 4; ++r) {                                        \
            const float v = St[g][r] * 0.125f;                                 \
            St[g][r] = v; mm = fmaxf(mm, v);                                   \
          }                                                                    \
      } else if (it_ == 0 && rowbase >= 192) {                                 \
        _Pragma("unroll")                                                      \
        for (int g = 0; g < 2; ++g)                                            \
          _Pragma("unroll")                                                    \
          for (int r = 0; r < 4; ++r) {                                        \
            const float v = St[g][r] * 0.125f;                                 \
            St[g][r] = v; mm = fmaxf(mm, v);                                   \
          }                                                                    \
        _Pragma("unroll")                                                      \
        for (int g = 2; g < 4; ++g)                                            \
          _Pragma("unroll")                                                    \
          for (int r = 0; r < 4; ++r) St[g][r] = -INFINITY;                    \
      } else {                                                                 \
        _Pragma("unroll")                                                      \
        for (int g = 0; g < 4; ++g)                                            \
          _Pragma("unroll")                                                    \
          for (int r = 0; r < 4; ++r) {                                        \
            float v = St[g][r] * 0.125f;                                       \
            const int col = c0 + g * 16 + quad * 4 + r;                        \
            int dd = row - col; dd = dd < 0 ? -dd : dd;                        \
            if (!(col < GLOBAL_TOK || dd <= WIN_HALF)) v = -INFINITY;          \
            St[g][r] = v; mm = fmaxf(mm, v);                                   \
          }                                                                    \
      }                                                                        \
      SOFTMAX_P_UPDATE(St)                                                     \
      bf16x8 vl[4], vh[4];                                                     \
      _Pragma("unroll")                                                        \
      for (int d = 0; d < 4; ++d) {                                            \
        vl[d] = *(const bf16x8*)&Vs[BUF][swz(n + d * 16, quad)];               \
        vh[d] = *(const bf16x8*)&Vs[BUF][swz(n + d * 16, quad + 4)];           \
      }                                                                        \
      asm volatile("s_waitcnt lgkmcnt(0)" ::: "memory");                       \
      __builtin_amdgcn_sched_barrier(0);                                       \
      __builtin_amdgcn_s_setprio(1);                                           \
      _Pragma("unroll")                                                        \
      for (int kg = 0; kg < 2; ++kg) {                                         \
        bf16x8 pf_ = *(const bf16x8*)&myPt[n * PT_STRIDE + kg * 32 + quad * 8];\
        _Pragma("unroll")                                                      \
        for (int d = 0; d < 4; ++d)                                            \
          O[d] = __builtin_amdgcn_mfma_f32_16x16x32_bf16(                      \
              kg ? vh[d] : vl[d], pf_, O[d], 0, 0, 0);                         \
      }                                                                        \
      __builtin_amdgcn_s_setprio(0);                                           \
    }                                                                          \
    if (it_ + 1 < NT) {                                                        \
      asm volatile("s_waitcnt vmcnt(0)" ::: "memory");                         \
      __builtin_amdgcn_sched_barrier(0);                                       \
      STAGE_WRITE((BUF) ^ 1, RW);                                              \
      if (it_ + 2 < NT) { STAGE_LOAD(blo + (it_ + 1) * 64, RL); }              \
      __syncthreads();                                                         \
    }                                                                          \
  }

__global__ __launch_bounds__(256, 3) void sparse_attn_mfma(
    const unsigned short* __restrict__ qkv,
    const unsigned short* __restrict__ vT,
    unsigned short* __restrict__ y,
    float* __restrict__ part)
{
    __shared__ unsigned short Ks[2][64 * 64];
    __shared__ unsigned short Vs[2][64 * 64];
    __shared__ unsigned short Pt[4][16 * PT_STRIDE];
    const int tid = threadIdx.x;
    const int w = tid >> 6, lane = tid & 63;
    const int quad = lane >> 4, n = lane & 15;
    const int bid = blockIdx.x;
    const f32x4 Zf = (f32x4){0.f, 0.f, 0.f, 0.f};

    if (bid >= 64) {
        // ---------------- windowed block path (bid 64..1087) ----------------
        const int wb = bid - 64;
        const int h = wb & 15;
        const int B = wb >> 4;             // [0,64)
        const int base = B * 64;
        const int rowbase = base + w * 16;
        const bool activeW = !(B == 0 && w < 2);   // rows 0-31 -> dense path
        int blo = base - 128; if (blo < 64) blo = 64;
        int bhi = base + 192; if (bhi > T_SEQ) bhi = T_SEQ;
        const int NT = 1 + (bhi - blo) / 64;

        const unsigned short* kb = qkv + C_DIM + h * 64;
        const unsigned short* vb = vT + (size_t)h * 64 * T_SEQ;
        unsigned short* myPt = Pt[w];

        const int srow = tid >> 3, scol = tid & 7;
        const int kdst0 = swz(srow, scol);
        const int kdst1 = kdst0 + 32 * 64;

        const unsigned short* qp = qkv + (size_t)(rowbase + n) * QKVW + h * 64 + quad * 8;
        bf16x8 q0 = *(const bf16x8*)qp;
        bf16x8 q1 = *(const bf16x8*)(qp + 32);

        f32x4 O[4];
        #pragma unroll
        for (int i = 0; i < 4; ++i) O[i] = (f32x4){0.f, 0.f, 0.f, 0.f};
        float m_run = -INFINITY, l_part = 0.f;
        const int row = rowbase + n;

        StReg r0, r1;
        STAGE_LOAD(0, r0);                 // tile 0 (global cols)
        asm volatile("s_waitcnt vmcnt(0)" ::: "memory");
        __builtin_amdgcn_sched_barrier(0);
        STAGE_WRITE(0, r0);
        STAGE_LOAD(blo, r1);               // tile 1 (NT >= 3 always)
        __syncthreads();

        int it = 0;
        for (;;) {
            WTILE(it, 0, r1, r0);
            if (++it >= NT) break;
            WTILE(it, 1, r0, r1);
            if (++it >= NT) break;
        }

        if (activeW) {
            float l_run = l_part;
            l_run += __shfl_xor(l_run, 16);
            l_run += __shfl_xor(l_run, 32);
            const float invL = 1.f / l_run;
            #pragma unroll
            for (int dblk = 0; dblk < 4; ++dblk)
                #pragma unroll
                for (int r = 0; r < 4; ++r)
                    y[(size_t)row * C_DIM + h * 64 + dblk * 16 + quad * 4 + r] =
                        f2bf(O[dblk][r] * invL);
        }
    } else {
        // ---------------- dense split-K path (bid 0..63, q-rows 0-31) -------
        const int idx = bid;               // [0,64)
        const int h = idx & 15;
        const int u = (idx >> 4) * 4 + w;  // [0,16)
        const int rt = u >> 3, split = u & 7;
        const int rowbase = rt * 16;
        const int n_tiles = 8;

        const unsigned short* qp = qkv + (size_t)(rowbase + n) * QKVW + h * 64 + quad * 8;
        bf16x8 q0 = *(const bf16x8*)qp;
        bf16x8 q1 = *(const bf16x8*)(qp + 32);

        const unsigned short* kb = qkv + C_DIM + h * 64;
        const unsigned short* vb = vT + (size_t)h * 64 * T_SEQ;
        unsigned short* myPt = Pt[w];

        f32x4 O[4];
        #pragma unroll
        for (int i = 0; i < 4; ++i) O[i] = (f32x4){0.f, 0.f, 0.f, 0.f};
        float m_run = -INFINITY, l_part = 0.f;

        KVbuf b0, b1;
        LOAD_KV(split * 512, b0);
        int it = 0;
        for (;;) {
            PROC_TILE(it, b0, b1);
            if (++it >= n_tiles) break;
            PROC_TILE(it, b1, b0);
            if (++it >= n_tiles) break;
        }

        float l_run = l_part;
        l_run += __shfl_xor(l_run, 16);
        l_run += __shfl_xor(l_run, 32);

        float* pb = part + ((size_t)(h * 2 + rt) * NSLOT + split) * 16 * PROW;
        #pragma unroll
        for (int dblk = 0; dblk < 4; ++dblk)
            #pragma unroll
            for (int r = 0; r < 4; ++r)
                pb[n * PROW + dblk * 16 + quad * 4 + r] = O[dblk][r];
        if (quad == 0) {
            pb[n * PROW + 64] = m_run;
            pb[n * PROW + 65] = l_run;
        }
    }
}

// Merge NSLOT partials per (head, 16-row tile) -> y rows 0..31.
__global__ __launch_bounds__(64) void attn_combine(
    const float* __restrict__ part, unsigned short* __restrict__ y)
{
    const int d = threadIdx.x;
    const int h = blockIdx.x >> 1, rt = blockIdx.x & 1;
    const float* base = part + (size_t)(h * 2 + rt) * NSLOT * 16 * PROW;
    for (int row = 0; row < 16; ++row) {
        float M = -INFINITY;
        for (int sl = 0; sl < NSLOT; ++sl)
            M = fmaxf(M, base[(size_t)sl * 16 * PROW + row * PROW + 64]);
        float L = 0.f, Od = 0.f;
        for (int sl = 0; sl < NSLOT; ++sl) {
            const float* p = base + (size_t)sl * 16 * PROW + row * PROW;
            const float s = __expf(p[64] - M);
            L += p[65] * s;
            Od += p[d] * s;
        }
        y[(size_t)(rt * 16 + row) * C_DIM + h * 64 + d] = f2bf(Od / L);
    }
}

extern "C" void kernel_launch(void* const* d_in, const int* in_sizes, int n_in,
                              void* d_out, int out_size, void* d_ws, size_t ws_size,
                              hipStream_t stream) {
    const float* x  = (const float*)d_in[0];
    const float* Wa = (const float*)d_in[1];
    const float* ba = (const float*)d_in[2];
    const float* Wp = (const float*)d_in[3];
    const float* bp = (const float*)d_in[4];
    float* out = (float*)d_out;

    // ws layout (ushort units):
    // xb 8MB, Wabt 6MB, Wpbt 2MB, qkv 24MB, yat 8MB, vT 8MB, part 1.2MB
    unsigned short* xb   = (unsigned short*)d_ws;                   // [4096,1024]
    unsigned short* Wabt = xb   + (size_t)T_SEQ * C_DIM;            // [3072,1024]
    unsigned short* Wpbt = Wabt + (size_t)C_DIM * QKVW;             // [1024,1024]
    unsigned short* qkv  = Wpbt + (size_t)C_DIM * C_DIM;            // [4096,3072]
    unsigned short* yat  = qkv  + (size_t)T_SEQ * QKVW;             // [4096,1024]
    unsigned short* vT   = yat  + (size_t)T_SEQ * C_DIM;            // [1024,4096]
    float* part = (float*)(vT + (size_t)C_DIM * T_SEQ);

    prep_kernel<<<4096 + 3072 + 1024, 256, 0, stream>>>(
        x, Wa, Wp, xb, Wabt, Wpbt);

    gemm_qkv_kernel<<<dim3(QKVW / 128, T_SEQ / 128), 256, 0, stream>>>(
        xb, Wabt, ba, qkv, vT, T_SEQ, QKVW, C_DIM);

    const int nBlocks = 1024 + 64;   // dense split-K first, then windowed
    sparse_attn_mfma<<<nBlocks, 256, 0, stream>>>(qkv, vT, yat, part);
    attn_combine<<<H_HEADS * 2, 64, 0, stream>>>(part, yat);

    gemm_proj_kernel<<<dim3(C_DIM / 128, T_SEQ / 128), 256, 0, stream>>>(
        yat, Wpbt, bp, out, nullptr, T_SEQ, C_DIM, C_DIM);
}